// Round 4
// baseline (687.592 us; speedup 1.0000x reference)
//
#include <hip/hip_runtime.h>
#include <hip/hip_bf16.h>

// GCN 2-layer forward on gfx950 — CSR via 2-level bucket sort (write-combined),
// gather aggregation, spill-free fp32 GEMMs.
//
//   layer 1: t = Ahat x (64 feats), h = relu(t W1 + b1)
//   layer 2: ys = dinv ⊙ (h W2)  (40 feats), out = dinv ⊙ (ys[d] + sum ys[s]) + b2
//
// R4: replaces k_zero/k_hist/k_scan*/k_permute (R3: 106MB amplified scatter
// writes, 125 us) with bhist -> bscan -> P1 (LDS-staged bucket partition,
// contiguous flushes) -> P2 (per-bucket LDS hist/scan/permute; random writes
// confined to one WG's 16KB window). Layer-2 gather needs no per-edge dinv
// (folded into gemm2 epilogue).

static constexpr int FIN = 64;
static constexpr int HID = 128;
static constexpr int CLS = 40;
static constexpr int NB_MAX = 392;   // buckets of 256 nodes; N<=100352
static constexpr int STAGE_C = 16;   // staged entries per bucket
static constexpr int P1_CHUNK = 3072;

// ---------------- CSR build ----------------

__global__ __launch_bounds__(256) void k_zero(int* __restrict__ p, int n) {
    int i = blockIdx.x * 256 + threadIdx.x;
    if (i < n) p[i] = 0;
}

// per-bucket histogram, LDS-aggregated (grid-stride)
__global__ __launch_bounds__(256) void k_bhist(const int* __restrict__ dst,
                                               int* __restrict__ bcnt, int E, int NB) {
    __shared__ int lh[NB_MAX];
    const int tid = threadIdx.x;
    for (int i = tid; i < NB; i += 256) lh[i] = 0;
    __syncthreads();
    const int stride = gridDim.x * 256;
    for (int e = blockIdx.x * 256 + tid; e < E; e += stride)
        atomicAdd(&lh[dst[e] >> 8], 1);
    __syncthreads();
    for (int i = tid; i < NB; i += 256)
        if (lh[i]) atomicAdd(&bcnt[i], lh[i]);
}

// exclusive scan of bcnt[NB] -> bbase (+ sentinel), init gcur
__global__ __launch_bounds__(512) void k_bscan(const int* __restrict__ bcnt,
                                               int* __restrict__ bbase,
                                               int* __restrict__ gcur, int NB) {
    __shared__ int sd[512];
    const int tid = threadIdx.x;
    int v = (tid < NB) ? bcnt[tid] : 0;
    sd[tid] = v;
    for (int off = 1; off < 512; off <<= 1) {
        __syncthreads();
        int t = (tid >= off) ? sd[tid - off] : 0;
        __syncthreads();
        sd[tid] += t;
    }
    __syncthreads();
    int excl = sd[tid] - v;
    if (tid < NB) { bbase[tid] = excl; gcur[tid] = excl; }
    if (tid == NB - 1) bbase[NB] = sd[tid];
}

// P1: partition edges into buckets (dst>>8). LDS staging, contiguous flushes.
__global__ __launch_bounds__(1024, 1) void k_p1(const int* __restrict__ ei,
                                                int* __restrict__ gcur,
                                                int2* __restrict__ tmp,
                                                int E, int NB, int per_wg) {
    __shared__ int2 stage[NB_MAX][STAGE_C];
    __shared__ int scnt[NB_MAX];
    const int tid = threadIdx.x;
    const int r0 = blockIdx.x * per_wg;
    const int r1 = min(E, r0 + per_wg);
    for (int c0 = r0; c0 < r1; c0 += P1_CHUNK) {
        const int c1 = min(r1, c0 + P1_CHUNK);
        for (int b = tid; b < NB; b += 1024) scnt[b] = 0;
        __syncthreads();
        for (int e = c0 + tid; e < c1; e += 1024) {
            int s = ei[e], d = ei[E + e];
            int b = d >> 8;
            int pos = atomicAdd(&scnt[b], 1);
            if (pos < STAGE_C) stage[b][pos] = make_int2(s, d);
            else {
                int g = atomicAdd(&gcur[b], 1);
                tmp[g] = make_int2(s, d);
            }
        }
        __syncthreads();
        const int wave = tid >> 6, lane = tid & 63;
        for (int b = wave; b < NB; b += 16) {
            int k = min(scnt[b], STAGE_C);
            if (k == 0) continue;
            int base = 0;
            if (lane == 0) base = atomicAdd(&gcur[b], k);
            base = __shfl(base, 0);
            if (lane < k) tmp[base + lane] = stage[b][lane];
        }
        __syncthreads();
    }
}

// P2: one WG per bucket — node hist, scan, rstart/cnt/dinv, permute -> ssrc.
__global__ __launch_bounds__(256) void k_p2(const int2* __restrict__ tmp,
                                            const int* __restrict__ bbase,
                                            int* __restrict__ rstart,
                                            int* __restrict__ cnt,
                                            float* __restrict__ dinv,
                                            int* __restrict__ ssrc, int N) {
    __shared__ int nh[256];
    __shared__ int sd[256];
    __shared__ int curs[256];
    const int tid = threadIdx.x;
    const int b = blockIdx.x;
    const int node0 = b << 8;
    const int e0 = bbase[b], e1 = bbase[b + 1];
    nh[tid] = 0;
    __syncthreads();
    for (int e = e0 + tid; e < e1; e += 256) {
        int2 p = tmp[e];
        atomicAdd(&nh[p.y - node0], 1);
    }
    __syncthreads();
    int v = nh[tid];
    sd[tid] = v;
    for (int off = 1; off < 256; off <<= 1) {
        __syncthreads();
        int t = (tid >= off) ? sd[tid - off] : 0;
        __syncthreads();
        sd[tid] += t;
    }
    __syncthreads();
    int rs = e0 + sd[tid] - v;   // exclusive within bucket + bucket base
    int node = node0 + tid;
    if (node < N) {
        rstart[node] = rs;
        cnt[node] = v;
        dinv[node] = rsqrtf((float)v + 1.0f);
    }
    curs[tid] = rs;
    __syncthreads();
    for (int e = e0 + tid; e < e1; e += 256) {
        int2 p = tmp[e];
        int slot = atomicAdd(&curs[p.y - node0], 1);
        ssrc[slot] = p.x;
    }
}

// ---------------- gather-aggregate: one wave per dst row ----------------
// !SCALED: out[d] = dinv[d]*( dinv[d]*X[d] + sum dinv[s]*X[s] ) (+bias)
//  SCALED: out[d] = dinv[d]*( X[d] + sum X[s] ) (+bias)   [X rows pre-scaled]

template <int F, bool BIAS, bool SCALED>
__global__ __launch_bounds__(256) void k_gather(const float* __restrict__ X,
                                                const float* __restrict__ dinv,
                                                const int* __restrict__ rstart,
                                                const int* __restrict__ cnt,
                                                const int* __restrict__ ssrc,
                                                const float* __restrict__ bias,
                                                float* __restrict__ out, int N) {
    int wid = (blockIdx.x * 256 + threadIdx.x) >> 6;
    int lane = threadIdx.x & 63;
    if (wid >= N) return;
    float dv = dinv[wid];
    int st = rstart[wid], c = cnt[wid];
    float xv = (F == 64 || lane < F) ? X[(size_t)wid * F + lane] : 0.f;
    float acc = SCALED ? xv : dv * xv;
    for (int base = 0; base < c; base += 64) {
        int m = min(64, c - base);
        int myS = 0;
        float myD = 0.f;
        if (lane < m) {
            myS = ssrc[st + base + lane];
            if (!SCALED) myD = dinv[myS];
        }
#pragma unroll 4
        for (int j = 0; j < m; ++j) {
            int s = __shfl(myS, j);
            float v = (F == 64 || lane < F) ? X[(size_t)s * F + lane] : 0.f;
            if (SCALED) acc += v;
            else        acc = fmaf(__shfl(myD, j), v, acc);
        }
    }
    if (F == 64 || lane < F) {
        float r = dv * acc;
        if (BIAS) r += bias[lane];
        out[(size_t)wid * F + lane] = r;
    }
}

// ---------------- GEMMs ----------------

// h = relu(t @ W1 + b1), 64-row tile, TM=8 x TN=4.
__global__ __launch_bounds__(256, 3) void k_gemm1(const float* __restrict__ A,
                                                  const float* __restrict__ W,
                                                  const float* __restrict__ bias,
                                                  float* __restrict__ H, int N) {
    __shared__ float Bs[FIN][132];
    __shared__ float As[64][68];
    const int tid = threadIdx.x;
    {
        const float4* W4 = (const float4*)W;
        for (int i = tid; i < 2048; i += 256) {
            int r = i >> 5, c4 = i & 31;
            *(float4*)&Bs[r][c4 * 4] = W4[i];
        }
    }
    const int row0 = blockIdx.x * 64;
    for (int i = tid; i < 1024; i += 256) {
        int r = i >> 4, c4 = i & 15;
        int gr = row0 + r;
        float4 v = make_float4(0.f, 0.f, 0.f, 0.f);
        if (gr < N) v = *(const float4*)&A[(size_t)gr * FIN + c4 * 4];
        *(float4*)&As[r][c4 * 4] = v;
    }
    __syncthreads();
    const int tc = tid & 31;
    const int tr = tid >> 5;
    float acc[8][4] = {};
#pragma unroll 2
    for (int k = 0; k < FIN; k += 4) {
        float4 bq[4];
#pragma unroll
        for (int kk = 0; kk < 4; ++kk) bq[kk] = *(const float4*)&Bs[k + kk][tc * 4];
#pragma unroll
        for (int i = 0; i < 8; ++i) {
            float4 a = *(const float4*)&As[tr * 8 + i][k];
            float* ac = acc[i];
            ac[0] = fmaf(a.x, bq[0].x, ac[0]); ac[0] = fmaf(a.y, bq[1].x, ac[0]);
            ac[0] = fmaf(a.z, bq[2].x, ac[0]); ac[0] = fmaf(a.w, bq[3].x, ac[0]);
            ac[1] = fmaf(a.x, bq[0].y, ac[1]); ac[1] = fmaf(a.y, bq[1].y, ac[1]);
            ac[1] = fmaf(a.z, bq[2].y, ac[1]); ac[1] = fmaf(a.w, bq[3].y, ac[1]);
            ac[2] = fmaf(a.x, bq[0].z, ac[2]); ac[2] = fmaf(a.y, bq[1].z, ac[2]);
            ac[2] = fmaf(a.z, bq[2].z, ac[2]); ac[2] = fmaf(a.w, bq[3].z, ac[2]);
            ac[3] = fmaf(a.x, bq[0].w, ac[3]); ac[3] = fmaf(a.y, bq[1].w, ac[3]);
            ac[3] = fmaf(a.z, bq[2].w, ac[3]); ac[3] = fmaf(a.w, bq[3].w, ac[3]);
        }
    }
    float4 bv = *(const float4*)&bias[tc * 4];
#pragma unroll
    for (int i = 0; i < 8; ++i) {
        int gr = row0 + tr * 8 + i;
        if (gr < N) {
            float4 v;
            v.x = fmaxf(acc[i][0] + bv.x, 0.f);
            v.y = fmaxf(acc[i][1] + bv.y, 0.f);
            v.z = fmaxf(acc[i][2] + bv.z, 0.f);
            v.w = fmaxf(acc[i][3] + bv.w, 0.f);
            *(float4*)&H[(size_t)gr * HID + tc * 4] = v;
        }
    }
}

// ys = dinv ⊙ (h @ W2). A from global (L1 broadcast), LDS = W2 only.
__global__ __launch_bounds__(256, 4) void k_gemm2(const float* __restrict__ H,
                                                  const float* __restrict__ W,
                                                  const float* __restrict__ dinv,
                                                  float* __restrict__ Y, int N) {
    __shared__ float Bs[CLS][132];
    const int tid = threadIdx.x;
    for (int i = tid; i < HID * CLS; i += 256) {
        int k = i / CLS, c = i - k * CLS;
        Bs[c][k] = W[i];
    }
    __syncthreads();
    const int row0 = blockIdx.x * 64;
    const int tc = tid & 7;
    const int tr = tid >> 3;
    const int r0 = row0 + tr * 2;
    const int ra = min(r0, N - 1);
    const int rb = min(r0 + 1, N - 1);
    float acc[2][5] = {};
#pragma unroll 2
    for (int k = 0; k < HID; k += 4) {
        float4 b[5];
#pragma unroll
        for (int j = 0; j < 5; ++j) b[j] = *(const float4*)&Bs[tc * 5 + j][k];
        float4 a0 = *(const float4*)&H[(size_t)ra * HID + k];
        float4 a1 = *(const float4*)&H[(size_t)rb * HID + k];
#pragma unroll
        for (int j = 0; j < 5; ++j) {
            acc[0][j] = fmaf(a0.x, b[j].x, fmaf(a0.y, b[j].y,
                        fmaf(a0.z, b[j].z, fmaf(a0.w, b[j].w, acc[0][j]))));
            acc[1][j] = fmaf(a1.x, b[j].x, fmaf(a1.y, b[j].y,
                        fmaf(a1.z, b[j].z, fmaf(a1.w, b[j].w, acc[1][j]))));
        }
    }
    float dva = dinv[ra], dvb = dinv[rb];
#pragma unroll
    for (int i = 0; i < 2; ++i) {
        int gr = r0 + i;
        float dv = (i == 0) ? dva : dvb;
        if (gr < N) {
#pragma unroll
            for (int j = 0; j < 5; ++j) Y[(size_t)gr * CLS + tc * 5 + j] = acc[i][j] * dv;
        }
    }
}

// ---------------- launch ----------------

extern "C" void kernel_launch(void* const* d_in, const int* in_sizes, int n_in,
                              void* d_out, int out_size, void* d_ws, size_t ws_size,
                              hipStream_t stream) {
    const float* x  = (const float*)d_in[0];
    const int*   ei = (const int*)d_in[1];   // [2][E]
    const float* W1 = (const float*)d_in[2];
    const float* b1 = (const float*)d_in[3];
    const float* W2 = (const float*)d_in[4];
    const float* b2 = (const float*)d_in[5];
    float* out = (float*)d_out;

    const int N = in_sizes[0] / FIN;
    const int E = in_sizes[1] / 2;
    const int NB = (N + 255) >> 8;

    float* dinv  = (float*)d_ws;                  // N
    float* t     = dinv + N;                      // N*FIN (reused as ys)
    float* h     = t + (size_t)N * FIN;           // N*HID  (tmp overlaps h)
    int* cnt     = (int*)(h + (size_t)N * HID);   // N
    int* rstart  = cnt + N;                       // N
    int* ssrc    = rstart + N;                    // E
    int* bcnt    = ssrc + E;                      // NB
    int* bbase   = bcnt + NB_MAX;                 // NB+1
    int* gcur    = bbase + NB_MAX + 1;            // NB
    int2* tmp    = (int2*)h;                      // E pairs (dead before gemm1)
    float* y     = t;

    dim3 blk(256);
    // CSR build: bucket sort by dst (write-combined)
    hipLaunchKernelGGL(k_zero,  dim3((NB + 255) / 256), blk, 0, stream, bcnt, NB);
    hipLaunchKernelGGL(k_bhist, dim3(256), blk, 0, stream, ei + E, bcnt, E, NB);
    hipLaunchKernelGGL(k_bscan, dim3(1), dim3(512), 0, stream, bcnt, bbase, gcur, NB);
    {
        const int per_wg = (E + 255) / 256;
        hipLaunchKernelGGL(k_p1, dim3(256), dim3(1024), 0, stream, ei, gcur, tmp, E, NB, per_wg);
    }
    hipLaunchKernelGGL(k_p2, dim3(NB), blk, 0, stream, tmp, bbase, rstart, cnt, dinv, ssrc, N);
    // layer 1: aggregate x (64) then GEMM+bias+relu
    hipLaunchKernelGGL((k_gather<FIN, false, false>), dim3((N + 3) / 4), blk, 0, stream,
                       x, dinv, rstart, cnt, ssrc, (const float*)nullptr, t, N);
    hipLaunchKernelGGL(k_gemm1, dim3((N + 63) / 64), blk, 0, stream, t, W1, b1, h, N);
    // layer 2: GEMM (scaled rows) then plain-sum aggregate + bias
    hipLaunchKernelGGL(k_gemm2, dim3((N + 63) / 64), blk, 0, stream, h, W2, dinv, y, N);
    hipLaunchKernelGGL((k_gather<CLS, true, true>), dim3((N + 3) / 4), blk, 0, stream,
                       y, dinv, rstart, cnt, ssrc, b2, out, N);
}

// Round 5
// 373.790 us; speedup vs baseline: 1.8395x; 1.8395x over previous
//
#include <hip/hip_runtime.h>
#include <hip/hip_bf16.h>

// GCN 2-layer forward on gfx950 — CSR via 2-pass radix partition (no global
// atomics, no staging), gather aggregation, spill-free fp32 GEMMs.
//
//   layer 1: t = Ahat x (64 feats), h = relu(t W1 + b1)
//   layer 2: ys = dinv ⊙ (h W2) (40), out = dinv ⊙ (ys[d] + sum ys[s]) + b2
//
// R5: k_p1 (R4, 334us: flush-loop + LDS-staging serialization, 594k bank
// conflicts) replaced by count/scan/scatter radix partition with per-(WG,
// bucket) reserved ranges; per edge: 2 coalesced loads + 1 LDS atomic +
// 1 packed-int store. Edge payload packed to 4B ((d&255)<<24 | s, N < 2^24).

static constexpr int FIN = 64;
static constexpr int HID = 128;
static constexpr int CLS = 40;
static constexpr int NB_MAX = 392;   // buckets of 256 nodes; N <= 100352
static constexpr int NWG_P = 256;    // partition workgroups

// ---------------- CSR build: radix partition by dst>>8 ----------------

// Pass A: per-WG bucket histogram -> cntmat[b][wg]
__global__ __launch_bounds__(1024) void k_cnt(const int* __restrict__ dst,
                                              int* __restrict__ cntmat,
                                              int E, int NB, int per_wg) {
    __shared__ int lh[NB_MAX];
    const int tid = threadIdx.x, wg = blockIdx.x;
    for (int i = tid; i < NB; i += 1024) lh[i] = 0;
    __syncthreads();
    const int r0 = wg * per_wg, r1 = min(E, r0 + per_wg);
    for (int e = r0 + tid; e < r1; e += 1024)
        atomicAdd(&lh[dst[e] >> 8], 1);
    __syncthreads();
    for (int b = tid; b < NB; b += 1024) cntmat[b * NWG_P + wg] = lh[b];
}

// Pass B1: exclusive scan of each bucket row (256 WG-counts) -> in place,
// bucket total -> btot[b].
__global__ __launch_bounds__(256) void k_bscan1(int* __restrict__ cntmat,
                                                int* __restrict__ btot) {
    __shared__ int sd[256];
    const int b = blockIdx.x, tid = threadIdx.x;
    int v = cntmat[b * NWG_P + tid];
    sd[tid] = v;
    for (int off = 1; off < 256; off <<= 1) {
        __syncthreads();
        int t = (tid >= off) ? sd[tid - off] : 0;
        __syncthreads();
        sd[tid] += t;
    }
    __syncthreads();
    cntmat[b * NWG_P + tid] = sd[tid] - v;
    if (tid == 255) btot[b] = sd[255];
}

// Pass B2: exclusive scan of bucket totals -> bbase (+E sentinel).
__global__ __launch_bounds__(512) void k_bscan2(const int* __restrict__ btot,
                                                int* __restrict__ bbase,
                                                int NB, int E) {
    __shared__ int sd[512];
    const int tid = threadIdx.x;
    int v = (tid < NB) ? btot[tid] : 0;
    sd[tid] = v;
    for (int off = 1; off < 512; off <<= 1) {
        __syncthreads();
        int t = (tid >= off) ? sd[tid - off] : 0;
        __syncthreads();
        sd[tid] += t;
    }
    __syncthreads();
    if (tid < NB) bbase[tid] = sd[tid] - v;
    if (tid == 0) bbase[NB] = E;
}

// Pass C: scatter to reserved ranges; packed 4B payload.
__global__ __launch_bounds__(1024) void k_scat(const int* __restrict__ ei,
                                               const int* __restrict__ cntmat,
                                               const int* __restrict__ bbase,
                                               unsigned* __restrict__ tmp,
                                               int E, int NB, int per_wg) {
    __shared__ int lcur[NB_MAX];
    const int tid = threadIdx.x, wg = blockIdx.x;
    for (int b = tid; b < NB; b += 1024)
        lcur[b] = cntmat[b * NWG_P + wg] + bbase[b];
    __syncthreads();
    const int r0 = wg * per_wg, r1 = min(E, r0 + per_wg);
    for (int e = r0 + tid; e < r1; e += 1024) {
        int s = ei[e], d = ei[E + e];
        int b = d >> 8;
        int pos = atomicAdd(&lcur[b], 1);
        tmp[pos] = ((unsigned)(d & 255) << 24) | (unsigned)s;
    }
}

// P2: one WG per bucket — node hist, scan, rstart/cnt/dinv, permute -> ssrc.
__global__ __launch_bounds__(256) void k_p2(const unsigned* __restrict__ tmp,
                                            const int* __restrict__ bbase,
                                            int* __restrict__ rstart,
                                            int* __restrict__ cnt,
                                            float* __restrict__ dinv,
                                            int* __restrict__ ssrc, int N) {
    __shared__ int nh[256];
    __shared__ int sd[256];
    __shared__ int curs[256];
    const int tid = threadIdx.x;
    const int b = blockIdx.x;
    const int node0 = b << 8;
    const int e0 = bbase[b], e1 = bbase[b + 1];
    nh[tid] = 0;
    __syncthreads();
    for (int e = e0 + tid; e < e1; e += 256)
        atomicAdd(&nh[tmp[e] >> 24], 1);
    __syncthreads();
    int v = nh[tid];
    sd[tid] = v;
    for (int off = 1; off < 256; off <<= 1) {
        __syncthreads();
        int t = (tid >= off) ? sd[tid - off] : 0;
        __syncthreads();
        sd[tid] += t;
    }
    __syncthreads();
    int rs = e0 + sd[tid] - v;
    int node = node0 + tid;
    if (node < N) {
        rstart[node] = rs;
        cnt[node] = v;
        dinv[node] = rsqrtf((float)v + 1.0f);
    }
    curs[tid] = rs;
    __syncthreads();
    for (int e = e0 + tid; e < e1; e += 256) {
        unsigned p = tmp[e];
        int slot = atomicAdd(&curs[p >> 24], 1);
        ssrc[slot] = (int)(p & 0xFFFFFFu);
    }
}

// ---------------- gather-aggregate: one wave per dst row ----------------
// !SCALED: out[d] = dinv[d]*( dinv[d]*X[d] + sum dinv[s]*X[s] ) (+bias)
//  SCALED: out[d] = dinv[d]*( X[d] + sum X[s] ) (+bias)   [X rows pre-scaled]

template <int F, bool BIAS, bool SCALED>
__global__ __launch_bounds__(256) void k_gather(const float* __restrict__ X,
                                                const float* __restrict__ dinv,
                                                const int* __restrict__ rstart,
                                                const int* __restrict__ cnt,
                                                const int* __restrict__ ssrc,
                                                const float* __restrict__ bias,
                                                float* __restrict__ out, int N) {
    int wid = (blockIdx.x * 256 + threadIdx.x) >> 6;
    int lane = threadIdx.x & 63;
    if (wid >= N) return;
    float dv = dinv[wid];
    int st = rstart[wid], c = cnt[wid];
    float xv = (F == 64 || lane < F) ? X[(size_t)wid * F + lane] : 0.f;
    float acc = SCALED ? xv : dv * xv;
    for (int base = 0; base < c; base += 64) {
        int m = min(64, c - base);
        int myS = 0;
        float myD = 0.f;
        if (lane < m) {
            myS = ssrc[st + base + lane];
            if (!SCALED) myD = dinv[myS];
        }
#pragma unroll 4
        for (int j = 0; j < m; ++j) {
            int s = __shfl(myS, j);
            float v = (F == 64 || lane < F) ? X[(size_t)s * F + lane] : 0.f;
            if (SCALED) acc += v;
            else        acc = fmaf(__shfl(myD, j), v, acc);
        }
    }
    if (F == 64 || lane < F) {
        float r = dv * acc;
        if (BIAS) r += bias[lane];
        out[(size_t)wid * F + lane] = r;
    }
}

// ---------------- GEMMs ----------------

// h = relu(t @ W1 + b1), 64-row tile, TM=8 x TN=4.
__global__ __launch_bounds__(256, 3) void k_gemm1(const float* __restrict__ A,
                                                  const float* __restrict__ W,
                                                  const float* __restrict__ bias,
                                                  float* __restrict__ H, int N) {
    __shared__ float Bs[FIN][132];
    __shared__ float As[64][68];
    const int tid = threadIdx.x;
    {
        const float4* W4 = (const float4*)W;
        for (int i = tid; i < 2048; i += 256) {
            int r = i >> 5, c4 = i & 31;
            *(float4*)&Bs[r][c4 * 4] = W4[i];
        }
    }
    const int row0 = blockIdx.x * 64;
    for (int i = tid; i < 1024; i += 256) {
        int r = i >> 4, c4 = i & 15;
        int gr = row0 + r;
        float4 v = make_float4(0.f, 0.f, 0.f, 0.f);
        if (gr < N) v = *(const float4*)&A[(size_t)gr * FIN + c4 * 4];
        *(float4*)&As[r][c4 * 4] = v;
    }
    __syncthreads();
    const int tc = tid & 31;
    const int tr = tid >> 5;
    float acc[8][4] = {};
#pragma unroll 2
    for (int k = 0; k < FIN; k += 4) {
        float4 bq[4];
#pragma unroll
        for (int kk = 0; kk < 4; ++kk) bq[kk] = *(const float4*)&Bs[k + kk][tc * 4];
#pragma unroll
        for (int i = 0; i < 8; ++i) {
            float4 a = *(const float4*)&As[tr * 8 + i][k];
            float* ac = acc[i];
            ac[0] = fmaf(a.x, bq[0].x, ac[0]); ac[0] = fmaf(a.y, bq[1].x, ac[0]);
            ac[0] = fmaf(a.z, bq[2].x, ac[0]); ac[0] = fmaf(a.w, bq[3].x, ac[0]);
            ac[1] = fmaf(a.x, bq[0].y, ac[1]); ac[1] = fmaf(a.y, bq[1].y, ac[1]);
            ac[1] = fmaf(a.z, bq[2].y, ac[1]); ac[1] = fmaf(a.w, bq[3].y, ac[1]);
            ac[2] = fmaf(a.x, bq[0].z, ac[2]); ac[2] = fmaf(a.y, bq[1].z, ac[2]);
            ac[2] = fmaf(a.z, bq[2].z, ac[2]); ac[2] = fmaf(a.w, bq[3].z, ac[2]);
            ac[3] = fmaf(a.x, bq[0].w, ac[3]); ac[3] = fmaf(a.y, bq[1].w, ac[3]);
            ac[3] = fmaf(a.z, bq[2].w, ac[3]); ac[3] = fmaf(a.w, bq[3].w, ac[3]);
        }
    }
    float4 bv = *(const float4*)&bias[tc * 4];
#pragma unroll
    for (int i = 0; i < 8; ++i) {
        int gr = row0 + tr * 8 + i;
        if (gr < N) {
            float4 v;
            v.x = fmaxf(acc[i][0] + bv.x, 0.f);
            v.y = fmaxf(acc[i][1] + bv.y, 0.f);
            v.z = fmaxf(acc[i][2] + bv.z, 0.f);
            v.w = fmaxf(acc[i][3] + bv.w, 0.f);
            *(float4*)&H[(size_t)gr * HID + tc * 4] = v;
        }
    }
}

// ys = dinv ⊙ (h @ W2). A from global (L1 broadcast), LDS = W2 only.
__global__ __launch_bounds__(256, 4) void k_gemm2(const float* __restrict__ H,
                                                  const float* __restrict__ W,
                                                  const float* __restrict__ dinv,
                                                  float* __restrict__ Y, int N) {
    __shared__ float Bs[CLS][132];
    const int tid = threadIdx.x;
    for (int i = tid; i < HID * CLS; i += 256) {
        int k = i / CLS, c = i - k * CLS;
        Bs[c][k] = W[i];
    }
    __syncthreads();
    const int row0 = blockIdx.x * 64;
    const int tc = tid & 7;
    const int tr = tid >> 3;
    const int r0 = row0 + tr * 2;
    const int ra = min(r0, N - 1);
    const int rb = min(r0 + 1, N - 1);
    float acc[2][5] = {};
#pragma unroll 2
    for (int k = 0; k < HID; k += 4) {
        float4 b[5];
#pragma unroll
        for (int j = 0; j < 5; ++j) b[j] = *(const float4*)&Bs[tc * 5 + j][k];
        float4 a0 = *(const float4*)&H[(size_t)ra * HID + k];
        float4 a1 = *(const float4*)&H[(size_t)rb * HID + k];
#pragma unroll
        for (int j = 0; j < 5; ++j) {
            acc[0][j] = fmaf(a0.x, b[j].x, fmaf(a0.y, b[j].y,
                        fmaf(a0.z, b[j].z, fmaf(a0.w, b[j].w, acc[0][j]))));
            acc[1][j] = fmaf(a1.x, b[j].x, fmaf(a1.y, b[j].y,
                        fmaf(a1.z, b[j].z, fmaf(a1.w, b[j].w, acc[1][j]))));
        }
    }
    float dva = dinv[ra], dvb = dinv[rb];
#pragma unroll
    for (int i = 0; i < 2; ++i) {
        int gr = r0 + i;
        float dv = (i == 0) ? dva : dvb;
        if (gr < N) {
#pragma unroll
            for (int j = 0; j < 5; ++j) Y[(size_t)gr * CLS + tc * 5 + j] = acc[i][j] * dv;
        }
    }
}

// ---------------- launch ----------------

extern "C" void kernel_launch(void* const* d_in, const int* in_sizes, int n_in,
                              void* d_out, int out_size, void* d_ws, size_t ws_size,
                              hipStream_t stream) {
    const float* x  = (const float*)d_in[0];
    const int*   ei = (const int*)d_in[1];   // [2][E]
    const float* W1 = (const float*)d_in[2];
    const float* b1 = (const float*)d_in[3];
    const float* W2 = (const float*)d_in[4];
    const float* b2 = (const float*)d_in[5];
    float* out = (float*)d_out;

    const int N = in_sizes[0] / FIN;
    const int E = in_sizes[1] / 2;
    const int NB = (N + 255) >> 8;
    const int per_wg = (E + NWG_P - 1) / NWG_P;

    float* dinv   = (float*)d_ws;                  // N
    float* t      = dinv + N;                      // N*FIN (reused as ys)
    float* h      = t + (size_t)N * FIN;           // N*HID (tmp overlaps)
    int* cnt      = (int*)(h + (size_t)N * HID);   // N
    int* rstart   = cnt + N;                       // N
    int* ssrc     = rstart + N;                    // E
    int* cntmat   = ssrc + E;                      // NB_MAX*NWG_P
    int* btot     = cntmat + NB_MAX * NWG_P;       // NB_MAX
    int* bbase    = btot + NB_MAX;                 // NB_MAX+1
    unsigned* tmp = (unsigned*)h;                  // E (dead before gemm1)
    float* y      = t;

    dim3 blk(256);
    // CSR build: radix partition by dst
    hipLaunchKernelGGL(k_cnt,    dim3(NWG_P), dim3(1024), 0, stream, ei + E, cntmat, E, NB, per_wg);
    hipLaunchKernelGGL(k_bscan1, dim3(NB), blk, 0, stream, cntmat, btot);
    hipLaunchKernelGGL(k_bscan2, dim3(1), dim3(512), 0, stream, btot, bbase, NB, E);
    hipLaunchKernelGGL(k_scat,   dim3(NWG_P), dim3(1024), 0, stream, ei, cntmat, bbase, tmp, E, NB, per_wg);
    hipLaunchKernelGGL(k_p2,     dim3(NB), blk, 0, stream, tmp, bbase, rstart, cnt, dinv, ssrc, N);
    // layer 1: aggregate x (64) then GEMM+bias+relu
    hipLaunchKernelGGL((k_gather<FIN, false, false>), dim3((N + 3) / 4), blk, 0, stream,
                       x, dinv, rstart, cnt, ssrc, (const float*)nullptr, t, N);
    hipLaunchKernelGGL(k_gemm1, dim3((N + 63) / 64), blk, 0, stream, t, W1, b1, h, N);
    // layer 2: GEMM (scaled rows) then plain-sum aggregate + bias
    hipLaunchKernelGGL(k_gemm2, dim3((N + 63) / 64), blk, 0, stream, h, W2, dinv, y, N);
    hipLaunchKernelGGL((k_gather<CLS, true, true>), dim3((N + 3) / 4), blk, 0, stream,
                       y, dinv, rstart, cnt, ssrc, b2, out, N);
}